// Round 1
// baseline (370.581 us; speedup 1.0000x reference)
//
#include <hip/hip_runtime.h>

#define B_ 8
#define C_ 128
#define CI_ 64
#define N_ 4096

typedef _Float16 f16x8 __attribute__((ext_vector_type(8)));
typedef __bf16  bf16x8 __attribute__((ext_vector_type(8)));
typedef float   f32x4  __attribute__((ext_vector_type(4)));

// ---------------------------------------------------------------------------
// K0: transpose x [B][C][N] fp32 -> xT [B][N][C] f16 (64x64 LDS tiles)
// ---------------------------------------------------------------------------
__global__ __launch_bounds__(256) void k_transpose(const float* __restrict__ x,
                                                   _Float16* __restrict__ xT)
{
    __shared__ float tile[64][65];
    int b = blockIdx.z, c0 = blockIdx.y * 64, n0 = blockIdx.x * 64;
    int tx = threadIdx.x & 63, ty = threadIdx.x >> 6;
#pragma unroll
    for (int i = 0; i < 16; i++) {
        int c = ty + i * 4;
        tile[c][tx] = x[((size_t)b * C_ + c0 + c) * N_ + n0 + tx];
    }
    __syncthreads();
#pragma unroll
    for (int i = 0; i < 16; i++) {
        int n = ty + i * 4;
        xT[((size_t)b * N_ + n0 + n) * C_ + c0 + tx] = (_Float16)tile[tx][n];
    }
}

// ---------------------------------------------------------------------------
// K0b: convert the four weight matrices fp32 -> f16 (each 8192 elems)
// ---------------------------------------------------------------------------
__global__ __launch_bounds__(256) void k_wconv(
    const float* __restrict__ thw, const float* __restrict__ phw,
    const float* __restrict__ gw,  const float* __restrict__ ww,
    _Float16* __restrict__ wTh, _Float16* __restrict__ wPh,
    _Float16* __restrict__ wG,  _Float16* __restrict__ wW)
{
    int i = blockIdx.x * 256 + threadIdx.x;   // 0..32767
    int which = i >> 13, j = i & 8191;
    if (which == 0)      wTh[j] = (_Float16)thw[j];
    else if (which == 1) wPh[j] = (_Float16)phw[j];
    else if (which == 2) wG[j]  = (_Float16)gw[j];
    else                 wW[j]  = (_Float16)ww[j];
}

// ---------------------------------------------------------------------------
// K1: projections.
//   th  [B][N][CI] f16 : theta_x  (A-layout rows n, used as QK^T A and B)
//   ph  [B][N][CI] f16 : phi_x^T  (same layout)
//   gT  [B][CI][N] f16 : g_x^T    (row ci contiguous in n, PV B-operand layout)
// MFMA 16x16x32 f16. Wave w handles a 16-row strip of the 64-row tile.
// ---------------------------------------------------------------------------
__global__ __launch_bounds__(256) void k_proj(
    const _Float16* __restrict__ xT,
    const _Float16* __restrict__ wTh, const _Float16* __restrict__ wPh,
    const _Float16* __restrict__ wG,
    const float* __restrict__ bTh, const float* __restrict__ bPh,
    const float* __restrict__ bG,
    _Float16* __restrict__ th, _Float16* __restrict__ ph,
    _Float16* __restrict__ gT)
{
    int b = blockIdx.y, n0 = blockIdx.x * 64;
    int tid = threadIdx.x, wave = tid >> 6, lane = tid & 63;
    int l16 = lane & 15, quad = lane >> 4;
    const _Float16* xTb = xT + (size_t)b * N_ * C_;
    const _Float16* aRow = xTb + (size_t)(n0 + wave * 16 + l16) * C_ + quad * 8;

#pragma unroll
    for (int p = 0; p < 2; p++) {
        const _Float16* w = p ? wPh : wTh;
        const float* bias = p ? bPh : bTh;
        _Float16* outp = p ? ph : th;
        f32x4 acc[4] = {};
#pragma unroll
        for (int kc = 0; kc < 4; kc++) {
            f16x8 a = *(const f16x8*)(aRow + kc * 32);
#pragma unroll
            for (int t = 0; t < 4; t++) {
                f16x8 bb = *(const f16x8*)(w + (size_t)(t * 16 + l16) * C_ + kc * 32 + quad * 8);
                acc[t] = __builtin_amdgcn_mfma_f32_16x16x32_f16(a, bb, acc[t], 0, 0, 0);
            }
        }
#pragma unroll
        for (int t = 0; t < 4; t++) {
            float bv = bias[t * 16 + l16];
#pragma unroll
            for (int r = 0; r < 4; r++) {
                int n = n0 + wave * 16 + quad * 4 + r;
                outp[((size_t)b * N_ + n) * CI_ + t * 16 + l16] = (_Float16)(acc[t][r] + bv);
            }
        }
    }
    // gT = g_w @ xT^T : output rows ci (wave strip), cols n -> coalesced [CI][N] store
    {
        f32x4 acc[4] = {};
#pragma unroll
        for (int kc = 0; kc < 4; kc++) {
            f16x8 a = *(const f16x8*)(wG + (size_t)(wave * 16 + l16) * C_ + kc * 32 + quad * 8);
#pragma unroll
            for (int t = 0; t < 4; t++) {
                f16x8 bb = *(const f16x8*)(xTb + (size_t)(n0 + t * 16 + l16) * C_ + kc * 32 + quad * 8);
                acc[t] = __builtin_amdgcn_mfma_f32_16x16x32_f16(a, bb, acc[t], 0, 0, 0);
            }
        }
#pragma unroll
        for (int t = 0; t < 4; t++) {
#pragma unroll
            for (int r = 0; r < 4; r++) {
                int ci = wave * 16 + quad * 4 + r;
                gT[((size_t)b * CI_ + ci) * N_ + n0 + t * 16 + l16] = (_Float16)(acc[t][r] + bG[ci]);
            }
        }
    }
}

// ---------------------------------------------------------------------------
// K2a: column-softmax denominators. Block owns 64 columns m; streams all n in
// 64-row chunks; D[m] = sum_n exp(f[n,m]) (no max-subtract: |f| <~ 16, safe in
// fp32). Then writes g2[ci][m] = g[ci][m] / D[m] in bf16.
// ---------------------------------------------------------------------------
__global__ __launch_bounds__(256) void k_stats(
    const _Float16* __restrict__ th, const _Float16* __restrict__ ph,
    const _Float16* __restrict__ gT, __bf16* __restrict__ g2)
{
    __shared__ float Dsum[64];
    int b = blockIdx.y, m0 = blockIdx.x * 64;
    int tid = threadIdx.x, wave = tid >> 6, lane = tid & 63;
    int l16 = lane & 15, quad = lane >> 4;
    if (tid < 64) Dsum[tid] = 0.0f;
    __syncthreads();
    const _Float16* thb = th + (size_t)b * N_ * CI_;
    const _Float16* phb = ph + (size_t)b * N_ * CI_;

    f16x8 Bf[4][2];              // fixed B fragments: this block's 64 phi columns
#pragma unroll
    for (int t = 0; t < 4; t++) {
        const _Float16* bp = phb + (size_t)(m0 + t * 16 + l16) * CI_ + quad * 8;
        Bf[t][0] = *(const f16x8*)(bp);
        Bf[t][1] = *(const f16x8*)(bp + 32);
    }
    float csum[4] = {0.f, 0.f, 0.f, 0.f};
    for (int nc = 0; nc < N_; nc += 64) {
        const _Float16* ar = thb + (size_t)(nc + wave * 16 + l16) * CI_ + quad * 8;
        f16x8 a0 = *(const f16x8*)(ar);
        f16x8 a1 = *(const f16x8*)(ar + 32);
#pragma unroll
        for (int t = 0; t < 4; t++) {
            f32x4 acc = {0.f, 0.f, 0.f, 0.f};
            acc = __builtin_amdgcn_mfma_f32_16x16x32_f16(a0, Bf[t][0], acc, 0, 0, 0);
            acc = __builtin_amdgcn_mfma_f32_16x16x32_f16(a1, Bf[t][1], acc, 0, 0, 0);
            csum[t] += __expf(acc[0]) + __expf(acc[1]) + __expf(acc[2]) + __expf(acc[3]);
        }
    }
    // butterfly over quads -> per-wave column sums, then cross-wave via LDS
#pragma unroll
    for (int t = 0; t < 4; t++) {
        float s = csum[t];
        s += __shfl_xor(s, 16);
        s += __shfl_xor(s, 32);
        if (quad == 0) atomicAdd(&Dsum[t * 16 + l16], s);
    }
    __syncthreads();
    if (tid < 64) Dsum[tid] = 1.0f / Dsum[tid];
    __syncthreads();
    const _Float16* gb = gT + (size_t)b * CI_ * N_ + m0;
    __bf16* g2b = g2 + (size_t)b * CI_ * N_ + m0;
#pragma unroll
    for (int i = 0; i < 16; i++) {
        int idx = tid + 256 * i;           // 64 ci x 64 m
        int ci = idx >> 6, m = idx & 63;
        g2b[(size_t)ci * N_ + m] = (__bf16)((float)gb[(size_t)ci * N_ + m] * Dsum[m]);
    }
}

// ---------------------------------------------------------------------------
// K2c: Y = exp(theta @ phi^T) @ g2. Block owns 64 rows n; streams m in 64-col
// chunks: S (f16 MFMA) -> exp -> bf16 P via per-wave LDS strip (C-layout ->
// A-layout transform; each wave touches only its own 16 rows, no barrier) ->
// PV (bf16 MFMA) accumulating Y in registers. Stores Y [B][N][CI] f16.
// ---------------------------------------------------------------------------
__global__ __launch_bounds__(256) void k_attn(
    const _Float16* __restrict__ th, const _Float16* __restrict__ ph,
    const __bf16* __restrict__ g2, _Float16* __restrict__ Yf)
{
    __shared__ __bf16 P[64 * 72];   // stride 72 to soften bank conflicts
    int b = blockIdx.y, n0 = blockIdx.x * 64;
    int tid = threadIdx.x, wave = tid >> 6, lane = tid & 63;
    int l16 = lane & 15, quad = lane >> 4;
    const _Float16* thb = th + (size_t)b * N_ * CI_;
    const _Float16* phb = ph + (size_t)b * N_ * CI_;
    const __bf16* g2b = g2 + (size_t)b * CI_ * N_;

    const _Float16* ar = thb + (size_t)(n0 + wave * 16 + l16) * CI_ + quad * 8;
    f16x8 A0 = *(const f16x8*)(ar);
    f16x8 A1 = *(const f16x8*)(ar + 32);
    f32x4 Yacc[4] = {};
    __bf16* Pw = P + wave * 16 * 72;

    for (int mc = 0; mc < N_; mc += 64) {
#pragma unroll
        for (int t = 0; t < 4; t++) {
            const _Float16* bp = phb + (size_t)(mc + t * 16 + l16) * CI_ + quad * 8;
            f16x8 B0 = *(const f16x8*)(bp);
            f16x8 B1 = *(const f16x8*)(bp + 32);
            f32x4 acc = {0.f, 0.f, 0.f, 0.f};
            acc = __builtin_amdgcn_mfma_f32_16x16x32_f16(A0, B0, acc, 0, 0, 0);
            acc = __builtin_amdgcn_mfma_f32_16x16x32_f16(A1, B1, acc, 0, 0, 0);
#pragma unroll
            for (int r = 0; r < 4; r++)
                Pw[(quad * 4 + r) * 72 + t * 16 + l16] = (__bf16)__expf(acc[r]);
        }
#pragma unroll
        for (int kc = 0; kc < 2; kc++) {
            bf16x8 a = *(const bf16x8*)(Pw + l16 * 72 + kc * 32 + quad * 8);
#pragma unroll
            for (int t = 0; t < 4; t++) {
                bf16x8 bb = *(const bf16x8*)(g2b + (size_t)(t * 16 + l16) * N_ + mc + kc * 32 + quad * 8);
                Yacc[t] = __builtin_amdgcn_mfma_f32_16x16x32_bf16(a, bb, Yacc[t], 0, 0, 0);
            }
        }
    }
#pragma unroll
    for (int t = 0; t < 4; t++)
#pragma unroll
        for (int r = 0; r < 4; r++)
            Yf[((size_t)b * N_ + n0 + wave * 16 + quad * 4 + r) * CI_ + t * 16 + l16] =
                (_Float16)Yacc[t][r];
}

// ---------------------------------------------------------------------------
// K3: out[b][c][n] = W_w @ Y^T + W_b + x. MFMA f16; wave w owns 32 C-rows.
// ---------------------------------------------------------------------------
__global__ __launch_bounds__(256) void k_out(
    const _Float16* __restrict__ wW, const float* __restrict__ Wb,
    const _Float16* __restrict__ Yf, const float* __restrict__ x,
    float* __restrict__ out)
{
    int b = blockIdx.y, n0 = blockIdx.x * 64;
    int tid = threadIdx.x, wave = tid >> 6, lane = tid & 63;
    int l16 = lane & 15, quad = lane >> 4;
    f16x8 Af[2][2];
#pragma unroll
    for (int rt = 0; rt < 2; rt++)
#pragma unroll
        for (int kc = 0; kc < 2; kc++)
            Af[rt][kc] = *(const f16x8*)(wW + (size_t)(wave * 32 + rt * 16 + l16) * CI_ + kc * 32 + quad * 8);
    f32x4 acc[2][4] = {};
#pragma unroll
    for (int t = 0; t < 4; t++) {
        const _Float16* yp = Yf + ((size_t)b * N_ + n0 + t * 16 + l16) * CI_;
        f16x8 b0 = *(const f16x8*)(yp + quad * 8);
        f16x8 b1 = *(const f16x8*)(yp + 32 + quad * 8);
#pragma unroll
        for (int rt = 0; rt < 2; rt++) {
            acc[rt][t] = __builtin_amdgcn_mfma_f32_16x16x32_f16(Af[rt][0], b0, acc[rt][t], 0, 0, 0);
            acc[rt][t] = __builtin_amdgcn_mfma_f32_16x16x32_f16(Af[rt][1], b1, acc[rt][t], 0, 0, 0);
        }
    }
#pragma unroll
    for (int rt = 0; rt < 2; rt++)
#pragma unroll
        for (int t = 0; t < 4; t++)
#pragma unroll
            for (int r = 0; r < 4; r++) {
                int c = wave * 32 + rt * 16 + quad * 4 + r;
                size_t o = ((size_t)b * C_ + c) * N_ + n0 + t * 16 + l16;
                out[o] = acc[rt][t][r] + Wb[c] + x[o];
            }
}

// ---------------------------------------------------------------------------
extern "C" void kernel_launch(void* const* d_in, const int* in_sizes, int n_in,
                              void* d_out, int out_size, void* d_ws, size_t ws_size,
                              hipStream_t stream)
{
    const float* x    = (const float*)d_in[0];
    const float* g_w  = (const float*)d_in[1];
    const float* g_b  = (const float*)d_in[2];
    const float* th_w = (const float*)d_in[3];
    const float* th_b = (const float*)d_in[4];
    const float* ph_w = (const float*)d_in[5];
    const float* ph_b = (const float*)d_in[6];
    const float* W_w  = (const float*)d_in[7];
    const float* W_b  = (const float*)d_in[8];
    float* out = (float*)d_out;

    char* ws = (char*)d_ws;
    _Float16* xT  = (_Float16*)(ws);                  // [B][N][C]  8.0 MiB
    _Float16* th  = (_Float16*)(ws + 8388608);        // [B][N][CI] 4 MiB
    _Float16* ph  = (_Float16*)(ws + 12582912);       // [B][N][CI] 4 MiB
    _Float16* gT  = (_Float16*)(ws + 16777216);       // [B][CI][N] 4 MiB
    __bf16*   g2  = (__bf16*)  (ws + 20971520);       // [B][CI][N] 4 MiB
    _Float16* Yf  = (_Float16*)(ws + 25165824);       // [B][N][CI] 4 MiB
    _Float16* wTh = (_Float16*)(ws + 29360128);
    _Float16* wPh = (_Float16*)(ws + 29376512);
    _Float16* wG  = (_Float16*)(ws + 29392896);
    _Float16* wW  = (_Float16*)(ws + 29409280);       // end ~29.4 MiB

    hipLaunchKernelGGL(k_transpose, dim3(64, 2, 8), dim3(256), 0, stream, x, xT);
    hipLaunchKernelGGL(k_wconv, dim3(128), dim3(256), 0, stream,
                       th_w, ph_w, g_w, W_w, wTh, wPh, wG, wW);
    hipLaunchKernelGGL(k_proj, dim3(64, 8), dim3(256), 0, stream,
                       xT, wTh, wPh, wG, th_b, ph_b, g_b, th, ph, gT);
    hipLaunchKernelGGL(k_stats, dim3(64, 8), dim3(256), 0, stream, th, ph, gT, g2);
    hipLaunchKernelGGL(k_attn, dim3(64, 8), dim3(256), 0, stream, th, ph, g2, Yf);
    hipLaunchKernelGGL(k_out, dim3(64, 8), dim3(256), 0, stream, wW, W_b, Yf, x, out);
}

// Round 2
// 234.584 us; speedup vs baseline: 1.5797x; 1.5797x over previous
//
#include <hip/hip_runtime.h>

#define B_ 8
#define C_ 128
#define CI_ 64
#define N_ 4096

typedef _Float16 f16x8 __attribute__((ext_vector_type(8)));
typedef _Float16 f16x4 __attribute__((ext_vector_type(4)));
typedef float   f32x4  __attribute__((ext_vector_type(4)));

// ---------------------------------------------------------------------------
// K0: transpose x [B][C][N] fp32 -> xT [B][N][C] f16 (64x64 LDS tiles)
// ---------------------------------------------------------------------------
__global__ __launch_bounds__(256) void k_transpose(const float* __restrict__ x,
                                                   _Float16* __restrict__ xT)
{
    __shared__ float tile[64][65];
    int b = blockIdx.z, c0 = blockIdx.y * 64, n0 = blockIdx.x * 64;
    int tx = threadIdx.x & 63, ty = threadIdx.x >> 6;
#pragma unroll
    for (int i = 0; i < 16; i++) {
        int c = ty + i * 4;
        tile[c][tx] = x[((size_t)b * C_ + c0 + c) * N_ + n0 + tx];
    }
    __syncthreads();
#pragma unroll
    for (int i = 0; i < 16; i++) {
        int n = ty + i * 4;
        xT[((size_t)b * N_ + n0 + n) * C_ + c0 + tx] = (_Float16)tile[tx][n];
    }
}

// ---------------------------------------------------------------------------
// K0b: convert the four weight matrices fp32 -> f16 (each 8192 elems)
// ---------------------------------------------------------------------------
__global__ __launch_bounds__(256) void k_wconv(
    const float* __restrict__ thw, const float* __restrict__ phw,
    const float* __restrict__ gw,  const float* __restrict__ ww,
    _Float16* __restrict__ wTh, _Float16* __restrict__ wPh,
    _Float16* __restrict__ wG,  _Float16* __restrict__ wW)
{
    int i = blockIdx.x * 256 + threadIdx.x;   // 0..32767
    int which = i >> 13, j = i & 8191;
    if (which == 0)      wTh[j] = (_Float16)thw[j];
    else if (which == 1) wPh[j] = (_Float16)phw[j];
    else if (which == 2) wG[j]  = (_Float16)gw[j];
    else                 wW[j]  = (_Float16)ww[j];
}

// ---------------------------------------------------------------------------
// K1: projections -> th [B][N][CI], ph [B][N][CI], gT [B][CI][N] (all f16)
// ---------------------------------------------------------------------------
__global__ __launch_bounds__(256) void k_proj(
    const _Float16* __restrict__ xT,
    const _Float16* __restrict__ wTh, const _Float16* __restrict__ wPh,
    const _Float16* __restrict__ wG,
    const float* __restrict__ bTh, const float* __restrict__ bPh,
    const float* __restrict__ bG,
    _Float16* __restrict__ th, _Float16* __restrict__ ph,
    _Float16* __restrict__ gT)
{
    int b = blockIdx.y, n0 = blockIdx.x * 64;
    int tid = threadIdx.x, wave = tid >> 6, lane = tid & 63;
    int l16 = lane & 15, quad = lane >> 4;
    const _Float16* xTb = xT + (size_t)b * N_ * C_;
    const _Float16* aRow = xTb + (size_t)(n0 + wave * 16 + l16) * C_ + quad * 8;

#pragma unroll
    for (int p = 0; p < 2; p++) {
        const _Float16* w = p ? wPh : wTh;
        const float* bias = p ? bPh : bTh;
        _Float16* outp = p ? ph : th;
        f32x4 acc[4] = {};
#pragma unroll
        for (int kc = 0; kc < 4; kc++) {
            f16x8 a = *(const f16x8*)(aRow + kc * 32);
#pragma unroll
            for (int t = 0; t < 4; t++) {
                f16x8 bb = *(const f16x8*)(w + (size_t)(t * 16 + l16) * C_ + kc * 32 + quad * 8);
                acc[t] = __builtin_amdgcn_mfma_f32_16x16x32_f16(a, bb, acc[t], 0, 0, 0);
            }
        }
#pragma unroll
        for (int t = 0; t < 4; t++) {
            float bv = bias[t * 16 + l16];
#pragma unroll
            for (int r = 0; r < 4; r++) {
                int n = n0 + wave * 16 + quad * 4 + r;
                outp[((size_t)b * N_ + n) * CI_ + t * 16 + l16] = (_Float16)(acc[t][r] + bv);
            }
        }
    }
    {
        f32x4 acc[4] = {};
#pragma unroll
        for (int kc = 0; kc < 4; kc++) {
            f16x8 a = *(const f16x8*)(wG + (size_t)(wave * 16 + l16) * C_ + kc * 32 + quad * 8);
#pragma unroll
            for (int t = 0; t < 4; t++) {
                f16x8 bb = *(const f16x8*)(xTb + (size_t)(n0 + t * 16 + l16) * C_ + kc * 32 + quad * 8);
                acc[t] = __builtin_amdgcn_mfma_f32_16x16x32_f16(a, bb, acc[t], 0, 0, 0);
            }
        }
#pragma unroll
        for (int t = 0; t < 4; t++) {
#pragma unroll
            for (int r = 0; r < 4; r++) {
                int ci = wave * 16 + quad * 4 + r;
                gT[((size_t)b * CI_ + ci) * N_ + n0 + t * 16 + l16] = (_Float16)(acc[t][r] + bG[ci]);
            }
        }
    }
}

// ---------------------------------------------------------------------------
// K2a: rD[b][m] = 1 / sum_n exp(f[n][m]).  Block owns 64 cols m; 4 waves each
// stream a 1024-row n-slice (register-prefetched); quad-shuffle + LDS reduce.
// ---------------------------------------------------------------------------
__global__ __launch_bounds__(256) void k_stats(
    const _Float16* __restrict__ th, const _Float16* __restrict__ ph,
    float* __restrict__ rD)
{
    __shared__ float Dp[4][64];
    int b = blockIdx.y, m0 = blockIdx.x * 64;
    int tid = threadIdx.x, wave = tid >> 6, lane = tid & 63;
    int l16 = lane & 15, quad = lane >> 4;
    const _Float16* thb = th + (size_t)b * N_ * CI_;
    const _Float16* phb = ph + (size_t)b * N_ * CI_;

    f16x8 Bp[4][2];                      // phi rows m0..m0+63 (B operands)
#pragma unroll
    for (int t = 0; t < 4; t++) {
        const _Float16* bp = phb + (size_t)(m0 + t * 16 + l16) * CI_ + quad * 8;
        Bp[t][0] = *(const f16x8*)(bp);
        Bp[t][1] = *(const f16x8*)(bp + 32);
    }
    float csum[4] = {0.f, 0.f, 0.f, 0.f};
    const _Float16* pA = thb + (size_t)(wave * 1024 + l16) * CI_ + quad * 8;
    f16x8 A0 = *(const f16x8*)pA, A1 = *(const f16x8*)(pA + 32);
    for (int nc = 0; nc < 64; nc++) {
        const _Float16* pN = pA + ((nc < 63) ? 1024 : 0);   // next 16 rows
        f16x8 nA0 = *(const f16x8*)pN, nA1 = *(const f16x8*)(pN + 32);
        pA = pN;
#pragma unroll
        for (int t = 0; t < 4; t++) {
            f32x4 s = {0.f, 0.f, 0.f, 0.f};
            s = __builtin_amdgcn_mfma_f32_16x16x32_f16(A0, Bp[t][0], s, 0, 0, 0);
            s = __builtin_amdgcn_mfma_f32_16x16x32_f16(A1, Bp[t][1], s, 0, 0, 0);
            csum[t] += __expf(s[0]) + __expf(s[1]) + __expf(s[2]) + __expf(s[3]);
        }
        A0 = nA0; A1 = nA1;
    }
#pragma unroll
    for (int t = 0; t < 4; t++) {
        float s = csum[t];
        s += __shfl_xor(s, 16);
        s += __shfl_xor(s, 32);
        if (quad == 0) Dp[wave][t * 16 + l16] = s;
    }
    __syncthreads();
    if (tid < 64) {
        float d = Dp[0][tid] + Dp[1][tid] + Dp[2][tid] + Dp[3][tid];
        rD[(size_t)b * N_ + m0 + tid] = 1.0f / d;
    }
}

// ---------------------------------------------------------------------------
// K2b: Y = softmax(f,axis=1) @ g, computed transposed: Y^T[ci][n].
// S^T = phi·theta^T via 16x16x32 f16 MFMA; its C/D layout (col=n=l16,
// row=m=quad*4+r) IS the B-operand layout of 16x16x16 f16 MFMA, so
// P = exp(S^T)*rD stays in registers (no LDS round-trip).  A-operand = g
// loaded 8B/lane from gT.  Block: 64 n, 4 waves m-split (1024 m each),
// register-prefetched stream, 2-stage LDS tree reduction at the end.
// ---------------------------------------------------------------------------
__global__ __launch_bounds__(256) void k_attn(
    const _Float16* __restrict__ th, const _Float16* __restrict__ ph,
    const _Float16* __restrict__ gT, const float* __restrict__ rD,
    _Float16* __restrict__ Yf)
{
    __shared__ float red[2][4096];       // 2 x 16 KiB reduction slots
    int b = blockIdx.y, n0 = blockIdx.x * 64;
    int tid = threadIdx.x, wave = tid >> 6, lane = tid & 63;
    int l16 = lane & 15, quad = lane >> 4;
    const _Float16* thb = th + (size_t)b * N_ * CI_;
    const _Float16* phb = ph + (size_t)b * N_ * CI_;
    const _Float16* gTb = gT + (size_t)b * CI_ * N_;
    const float*    rDb = rD + (size_t)b * N_;

    f16x8 Bt[4][2];                      // theta rows n0..n0+63 (fixed B ops)
#pragma unroll
    for (int nt = 0; nt < 4; nt++) {
        const _Float16* bp = thb + (size_t)(n0 + nt * 16 + l16) * CI_ + quad * 8;
        Bt[nt][0] = *(const f16x8*)(bp);
        Bt[nt][1] = *(const f16x8*)(bp + 32);
    }
    f32x4 Y[4][4] = {};                  // [ci_tile][n_tile]

    const int m0 = wave * 1024;
    const _Float16* pA = phb + (size_t)(m0 + l16) * CI_ + quad * 8;
    const _Float16* pG0 = gTb + (size_t)(l16) * N_ + m0 + quad * 4;
    f16x8 A0 = *(const f16x8*)pA, A1 = *(const f16x8*)(pA + 32);
    f32x4 rd = *(const f32x4*)(rDb + m0 + quad * 4);
    f16x4 gf[4];
#pragma unroll
    for (int ct = 0; ct < 4; ct++)
        gf[ct] = *(const f16x4*)(pG0 + (size_t)(ct * 16) * N_);

    for (int mc = 0; mc < 64; mc++) {
        int step = (mc < 63) ? 16 : 0;
        const _Float16* pAn = pA + (size_t)step * CI_;
        f16x8 nA0 = *(const f16x8*)pAn, nA1 = *(const f16x8*)(pAn + 32);
        f32x4 nrd = *(const f32x4*)(rDb + m0 + mc * 16 + step + quad * 4);
        const _Float16* pGn = pG0 + mc * 16 + step;
        f16x4 ngf[4];
#pragma unroll
        for (int ct = 0; ct < 4; ct++)
            ngf[ct] = *(const f16x4*)(pGn + (size_t)(ct * 16) * N_);
        pA = pAn;

        f32x4 S[4];
#pragma unroll
        for (int nt = 0; nt < 4; nt++) {
            f32x4 z = {0.f, 0.f, 0.f, 0.f};
            z = __builtin_amdgcn_mfma_f32_16x16x32_f16(A0, Bt[nt][0], z, 0, 0, 0);
            S[nt] = __builtin_amdgcn_mfma_f32_16x16x32_f16(A1, Bt[nt][1], z, 0, 0, 0);
        }
        f16x4 P[4];
#pragma unroll
        for (int nt = 0; nt < 4; nt++)
#pragma unroll
            for (int r = 0; r < 4; r++)
                P[nt][r] = (_Float16)(__expf(S[nt][r]) * rd[r]);
#pragma unroll
        for (int ct = 0; ct < 4; ct++)
#pragma unroll
            for (int nt = 0; nt < 4; nt++)
                Y[ct][nt] = __builtin_amdgcn_mfma_f32_16x16x16f16(gf[ct], P[nt], Y[ct][nt], 0, 0, 0);

        A0 = nA0; A1 = nA1; rd = nrd;
#pragma unroll
        for (int ct = 0; ct < 4; ct++) gf[ct] = ngf[ct];
    }

    // ---- cross-wave reduction: (w0+w2), (w1+w3), then final combine ----
    if (wave >= 2) {
        float* s = &red[wave - 2][lane * 4];
#pragma unroll
        for (int ct = 0; ct < 4; ct++)
#pragma unroll
            for (int nt = 0; nt < 4; nt++)
                *(f32x4*)(s + (ct * 4 + nt) * 256) = Y[ct][nt];
    }
    __syncthreads();
    if (wave < 2) {
        float* s = &red[wave][lane * 4];
#pragma unroll
        for (int ct = 0; ct < 4; ct++)
#pragma unroll
            for (int nt = 0; nt < 4; nt++) {
                Y[ct][nt] += *(const f32x4*)(s + (ct * 4 + nt) * 256);
                *(f32x4*)(s + (ct * 4 + nt) * 256) = Y[ct][nt];
            }
    }
    __syncthreads();
    // cooperative store: thread t -> row n = t>>2, ci block = (t&3)*16
    {
        int n = tid >> 2, cb = tid & 3;
        int l16s = n & 15, tb = cb * 4 + (n >> 4);
        _Float16 vals[16];
#pragma unroll
        for (int j = 0; j < 16; j++) {
            int idx = tb * 256 + ((j >> 2) * 16 + l16s) * 4 + (j & 3);
            vals[j] = (_Float16)(red[0][idx] + red[1][idx]);
        }
        _Float16* yp = Yf + ((size_t)b * N_ + n0 + n) * CI_ + cb * 16;
        *(f16x8*)(yp)     = *(f16x8*)&vals[0];
        *(f16x8*)(yp + 8) = *(f16x8*)&vals[8];
    }
}

// ---------------------------------------------------------------------------
// K3: out[b][c][n] = W_w @ Y^T + W_b + x (residual).
// ---------------------------------------------------------------------------
__global__ __launch_bounds__(256) void k_out(
    const _Float16* __restrict__ wW, const float* __restrict__ Wb,
    const _Float16* __restrict__ Yf, const float* __restrict__ x,
    float* __restrict__ out)
{
    int b = blockIdx.y, n0 = blockIdx.x * 64;
    int tid = threadIdx.x, wave = tid >> 6, lane = tid & 63;
    int l16 = lane & 15, quad = lane >> 4;
    f16x8 Af[2][2];
#pragma unroll
    for (int rt = 0; rt < 2; rt++)
#pragma unroll
        for (int kc = 0; kc < 2; kc++)
            Af[rt][kc] = *(const f16x8*)(wW + (size_t)(wave * 32 + rt * 16 + l16) * CI_ + kc * 32 + quad * 8);
    f32x4 acc[2][4] = {};
#pragma unroll
    for (int t = 0; t < 4; t++) {
        const _Float16* yp = Yf + ((size_t)b * N_ + n0 + t * 16 + l16) * CI_;
        f16x8 b0 = *(const f16x8*)(yp + quad * 8);
        f16x8 b1 = *(const f16x8*)(yp + 32 + quad * 8);
#pragma unroll
        for (int rt = 0; rt < 2; rt++) {
            acc[rt][t] = __builtin_amdgcn_mfma_f32_16x16x32_f16(Af[rt][0], b0, acc[rt][t], 0, 0, 0);
            acc[rt][t] = __builtin_amdgcn_mfma_f32_16x16x32_f16(Af[rt][1], b1, acc[rt][t], 0, 0, 0);
        }
    }
#pragma unroll
    for (int rt = 0; rt < 2; rt++)
#pragma unroll
        for (int t = 0; t < 4; t++)
#pragma unroll
            for (int r = 0; r < 4; r++) {
                int c = wave * 32 + rt * 16 + quad * 4 + r;
                size_t o = ((size_t)b * C_ + c) * N_ + n0 + t * 16 + l16;
                out[o] = acc[rt][t][r] + Wb[c] + x[o];
            }
}

// ---------------------------------------------------------------------------
extern "C" void kernel_launch(void* const* d_in, const int* in_sizes, int n_in,
                              void* d_out, int out_size, void* d_ws, size_t ws_size,
                              hipStream_t stream)
{
    const float* x    = (const float*)d_in[0];
    const float* g_w  = (const float*)d_in[1];
    const float* g_b  = (const float*)d_in[2];
    const float* th_w = (const float*)d_in[3];
    const float* th_b = (const float*)d_in[4];
    const float* ph_w = (const float*)d_in[5];
    const float* ph_b = (const float*)d_in[6];
    const float* W_w  = (const float*)d_in[7];
    const float* W_b  = (const float*)d_in[8];
    float* out = (float*)d_out;

    char* ws = (char*)d_ws;
    _Float16* xT  = (_Float16*)(ws);                  // [B][N][C]  8 MiB
    _Float16* th  = (_Float16*)(ws + 8388608);        // [B][N][CI] 4 MiB
    _Float16* ph  = (_Float16*)(ws + 12582912);       // [B][N][CI] 4 MiB
    _Float16* gT  = (_Float16*)(ws + 16777216);       // [B][CI][N] 4 MiB
    _Float16* Yf  = (_Float16*)(ws + 20971520);       // [B][N][CI] 4 MiB
    float*    rD  = (float*)   (ws + 25165824);       // [B][N]     128 KiB
    _Float16* wTh = (_Float16*)(ws + 25296896);
    _Float16* wPh = (_Float16*)(ws + 25313280);
    _Float16* wG  = (_Float16*)(ws + 25329664);
    _Float16* wW  = (_Float16*)(ws + 25346048);       // end ~25.4 MiB

    hipLaunchKernelGGL(k_transpose, dim3(64, 2, 8), dim3(256), 0, stream, x, xT);
    hipLaunchKernelGGL(k_wconv, dim3(128), dim3(256), 0, stream,
                       th_w, ph_w, g_w, W_w, wTh, wPh, wG, wW);
    hipLaunchKernelGGL(k_proj, dim3(64, 8), dim3(256), 0, stream,
                       xT, wTh, wPh, wG, th_b, ph_b, g_b, th, ph, gT);
    hipLaunchKernelGGL(k_stats, dim3(64, 8), dim3(256), 0, stream, th, ph, rD);
    hipLaunchKernelGGL(k_attn, dim3(64, 8), dim3(256), 0, stream, th, ph, gT, rD, Yf);
    hipLaunchKernelGGL(k_out, dim3(64, 8), dim3(256), 0, stream, wW, W_b, Yf, x, out);
}